// Round 12
// baseline (541.953 us; speedup 1.0000x reference)
//
#include <hip/hip_runtime.h>
#include <cstdio>

#define NN 50000
#define NE 800000
#define DD 256
#define WS_NEED 113080000UL

__attribute__((constructor)) static void r12_on_load(void) {
    fprintf(stderr, "R12SO_LOADED\n");
    fflush(stderr);
}

__device__ float b2f(unsigned short u) {
    union { unsigned int i; float f; } c;
    c.i = ((unsigned int)u) << 16;
    return c.f;
}
__device__ float clampf(float v) { return fminf(fmaxf(v, -65504.f), 65504.f); }
__device__ float rdF(const void* p, long long idx, int ff) {
    if (ff) return clampf(b2f(((const unsigned short*)p)[idx]));
    return clampf(((const float*)p)[idx]);
}

__global__ void g_zero(int* deg, float* sums) {
    int i = blockIdx.x * 256 + threadIdx.x;
    if (i < NN) deg[i] = 0;
    if (i < 2 * DD) sums[i] = 0.f;
}

/* dtype detection (round 10 measured: fp32 x, int32 edges — kept as cheap guard) */
__global__ void g_detect(const unsigned short* xr, const int* ei, int* flags) {
    __shared__ int acc[2];
    if (threadIdx.x < 2) acc[threadIdx.x] = 0;
    __syncthreads();
    int g = 0;
    for (int j = 0; j < 4; j++) {
        unsigned short u = xr[(threadIdx.x * 4 + j) * 2];
        int e = (u >> 7) & 0xFF;
        if (u == 0 || u == 0x8000 || (e >= 100 && e <= 140)) g++;
    }
    atomicAdd(&acc[0], g);
    if (ei[2 * threadIdx.x + 1] != 0) atomicAdd(&acc[1], 1);
    __syncthreads();
    if (threadIdx.x == 0) {
        flags[0] = (acc[0] >= 922) ? 1 : 0; /* 1 => bf16 floats */
        flags[1] = (acc[1] == 0) ? 1 : 0;   /* 1 => int64 edges */
    }
}

__global__ void g_cvt_e(const int* raw, const int* flags, int* e32) {
    int i = blockIdx.x * 256 + threadIdx.x;
    if (i < 2 * NE) e32[i] = flags[1] ? raw[2 * i] : raw[i];
}

__global__ void g_cvt_w(const void* W, const int* flags, float* Wt) {
    Wt[threadIdx.x * DD + blockIdx.x] =
        rdF(W, (long long)blockIdx.x * DD + threadIdx.x, flags[0]);
}

__global__ void g_cvt_p(const void* bias, const void* gamma, const void* beta,
                        const int* flags, float* pf) {
    int t = threadIdx.x;
    int ff = flags[0];
    pf[t] = rdF(bias, t, ff);
    pf[DD + t] = rdF(gamma, t, ff);
    pf[2 * DD + t] = rdF(beta, t, ff);
}

/* GEMM: h[n][o] = sum_k x[n][k] * W[o][k]; Wt is [k][o]; h kept fp32 */
__global__ __launch_bounds__(256) void g_gemm(const void* x, const int* flags,
                                              const float* Wt, float* h) {
    __shared__ float xs[8 * DD];
    int t = threadIdx.x;
    int n0 = blockIdx.x * 8;
    int ff = flags[0];
    int j, k;
    for (j = 0; j < 8; j++) xs[j * DD + t] = rdF(x, (long long)(n0 + j) * DD + t, ff);
    __syncthreads();
    float acc[8];
    for (j = 0; j < 8; j++) acc[j] = 0.f;
    for (k = 0; k < DD; k++) {
        float wv = Wt[k * DD + t];
        for (j = 0; j < 8; j++) acc[j] += xs[j * DD + k] * wv;
    }
    for (j = 0; j < 8; j++)
        h[(unsigned long long)(n0 + j) * DD + t] = acc[j];
}

__global__ void g_degree(const int* erow, const int* ecol, int* deg) {
    int e = blockIdx.x * 256 + threadIdx.x;
    if (e < NE) {
        unsigned int c = (unsigned int)ecol[e];
        unsigned int r = (unsigned int)erow[e];
        if (c < NN && r < NN) atomicAdd(&deg[c], 1);
    }
}

__global__ void g_dinv(const int* deg, float* dinv) {
    int n = blockIdx.x * 256 + threadIdx.x;
    if (n < NN) dinv[n] = rsqrtf((float)(deg[n] + 1));
}

__global__ __launch_bounds__(256) void g_scan1(const int* deg, int* off, int* bsum) {
    __shared__ int sm[256];
    int tid = threadIdx.x;
    int i = blockIdx.x * 256 + tid;
    int v = (i < NN) ? deg[i] : 0;
    sm[tid] = v;
    __syncthreads();
    for (int s = 1; s < 256; s <<= 1) {
        int t = (tid >= s) ? sm[tid - s] : 0;
        __syncthreads();
        sm[tid] += t;
        __syncthreads();
    }
    if (i < NN) off[i] = sm[tid] - v;
    if (tid == 255) bsum[blockIdx.x] = sm[255];
}

__global__ __launch_bounds__(256) void g_scan2(const int* bsum, int* bbase) {
    __shared__ int sm[256];
    int tid = threadIdx.x;
    int v = (tid < 196) ? bsum[tid] : 0;
    sm[tid] = v;
    __syncthreads();
    for (int s = 1; s < 256; s <<= 1) {
        int t = (tid >= s) ? sm[tid - s] : 0;
        __syncthreads();
        sm[tid] += t;
        __syncthreads();
    }
    if (tid < 196) bbase[tid] = sm[tid] - v;
}

__global__ void g_scan3(int* off, const int* bbase, int* cursor) {
    int i = blockIdx.x * 256 + threadIdx.x;
    if (i < NN) {
        int o = off[i] + bbase[i >> 8];
        off[i] = o;
        cursor[i] = o;
    }
}

__global__ void g_fill(const int* erow, const int* ecol, int* cursor, int* csrc) {
    int e = blockIdx.x * 256 + threadIdx.x;
    if (e < NE) {
        unsigned int c = (unsigned int)ecol[e];
        unsigned int r = (unsigned int)erow[e];
        if (c < NN && r < NN) {
            int slot = atomicAdd(&cursor[c], 1);
            if ((unsigned int)slot < NE) csrc[slot] = (int)r;
        }
    }
}

/* aggregate + bias -> fp32 agg. one wave per node, lane owns 4 features */
__global__ __launch_bounds__(256) void g_agg(const float* h, const float* dinv,
                                             const int* off, const int* deg,
                                             const int* csrc, const float* pf,
                                             float* agg) {
    int lane = threadIdx.x & 63;
    int n = blockIdx.x * 4 + (threadIdx.x >> 6);
    int f0 = lane * 4;
    float dn = dinv[n];
    float ws = dn * dn;
    const float* hp = h + (unsigned long long)n * DD + f0;
    float a0 = hp[0] * ws;
    float a1 = hp[1] * ws;
    float a2 = hp[2] * ws;
    float a3 = hp[3] * ws;
    int s = off[n];
    int cnt = deg[n];
    for (int i = 0; i < cnt; i++) {
        int src = csrc[s + i];
        if ((unsigned int)src >= NN) continue;
        float wgt = dinv[src] * dn;
        const float* hq = h + (unsigned long long)src * DD + f0;
        a0 += hq[0] * wgt;
        a1 += hq[1] * wgt;
        a2 += hq[2] * wgt;
        a3 += hq[3] * wgt;
    }
    float* op = agg + (unsigned long long)n * DD + f0;
    op[0] = a0 + pf[f0 + 0];
    op[1] = a1 + pf[f0 + 1];
    op[2] = a2 + pf[f0 + 2];
    op[3] = a3 + pf[f0 + 3];
}

__global__ __launch_bounds__(256) void g_stats(const float* agg, float* sums) {
    int t = threadIdx.x;
    float s = 0.f;
    float s2 = 0.f;
    for (int n = blockIdx.x; n < NN; n += 256) {
        float v = agg[(unsigned long long)n * DD + t];
        s += v;
        s2 += v * v;
    }
    atomicAdd(&sums[t], s);
    atomicAdd(&sums[DD + t], s2);
}

__global__ void g_fin(const float* sums, const float* pf, float* ss) {
    int t = threadIdx.x;
    float mean = sums[t] * (1.0f / NN);
    float var = sums[DD + t] * (1.0f / NN) - mean * mean;
    var = fmaxf(var, 0.f);
    float sc = pf[DD + t] * rsqrtf(var + 1e-5f);
    ss[t] = sc;
    ss[DD + t] = pf[2 * DD + t] - mean * sc;
}

/* BN + ReLU: fp32 agg -> FP32 out (the harness's output dtype — round 11 evidence) */
__global__ void DenseGCNLayer_2937757631000_kernel(const float* agg, const float* ss,
                                                   float* out) {
    int t = threadIdx.x;
    unsigned long long i = (unsigned long long)blockIdx.x * DD + t;
    float v = agg[i];
    out[i] = fmaxf(ss[t] * v + ss[DD + t], 0.f);
}

extern "C" void kernel_launch(void* const* d_in, const int* in_sizes, int n_in,
                              void* d_out, int out_size, void* d_ws, size_t ws_size,
                              hipStream_t stream) {
    const void* x = d_in[0];
    const int* ei = (const int*)d_in[1];
    const void* W = d_in[2];
    const void* bias = d_in[3];
    const void* gamma = d_in[4];
    const void* beta = d_in[5];
    char* ws = (char*)d_ws;
    float* out = (float*)d_out;

    float* h = (float*)(ws + 0UL);            /* 51.2 MB fp32 */
    float* agg = (float*)(ws + 51200000UL);   /* 51.2 MB fp32 */
    int* e32 = (int*)(ws + 102400000UL);      /* 6.4 MB */
    int* csrc = (int*)(ws + 108800000UL);     /* 3.2 MB */
    float* Wt = (float*)(ws + 112000000UL);   /* 256 KB */
    int* deg = (int*)(ws + 112262144UL);
    float* dinv = (float*)(ws + 112462336UL);
    int* off = (int*)(ws + 112662528UL);
    int* cursor = (int*)(ws + 112862720UL);
    int* bsum = (int*)(ws + 113062912UL);
    int* bbase = (int*)(ws + 113063936UL);
    float* pf = (float*)(ws + 113064960UL);
    float* sums = (float*)(ws + 113068032UL);
    float* ss = (float*)(ws + 113070080UL);
    int* flags = (int*)(ws + 113072128UL);
    const int* erow = e32;
    const int* ecol = e32 + NE;

    if (ws_size < WS_NEED) {
        fprintf(stderr, "R12_WS_SMALL %zu\n", ws_size);
        fflush(stderr);
        return;
    }

    g_zero<<<196, 256, 0, stream>>>(deg, sums);
    g_detect<<<1, 256, 0, stream>>>((const unsigned short*)x, ei, flags);
    g_cvt_e<<<6250, 256, 0, stream>>>(ei, flags, e32);
    g_cvt_w<<<DD, DD, 0, stream>>>(W, flags, Wt);
    g_cvt_p<<<1, 256, 0, stream>>>(bias, gamma, beta, flags, pf);
    g_gemm<<<6250, 256, 0, stream>>>(x, flags, Wt, h);
    g_degree<<<3125, 256, 0, stream>>>(erow, ecol, deg);
    g_dinv<<<196, 256, 0, stream>>>(deg, dinv);
    g_scan1<<<196, 256, 0, stream>>>(deg, off, bsum);
    g_scan2<<<1, 256, 0, stream>>>(bsum, bbase);
    g_scan3<<<196, 256, 0, stream>>>(off, bbase, cursor);
    g_fill<<<3125, 256, 0, stream>>>(erow, ecol, cursor, csrc);
    g_agg<<<12500, 256, 0, stream>>>(h, dinv, off, deg, csrc, pf, agg);
    g_stats<<<256, 256, 0, stream>>>(agg, sums);
    g_fin<<<1, 256, 0, stream>>>(sums, pf, ss);
    DenseGCNLayer_2937757631000_kernel<<<50000, 256, 0, stream>>>(agg, ss, out);
}